// Round 1
// 357.384 us; speedup vs baseline: 1.0130x; 1.0130x over previous
//
#include <hip/hip_runtime.h>

#define EPS 1e-5f

// B=32, C=256, CC=64, template 14x14, search 64x64, K=7, 32 groups (2ch/group)

typedef __attribute__((ext_vector_type(8))) short short8;
typedef __attribute__((ext_vector_type(4))) float floatx4;

__device__ __forceinline__ unsigned short f2bf(float x) {
    union { float f; unsigned u; } v; v.f = x;
    unsigned r = v.u + 0x7FFFu + ((v.u >> 16) & 1u);   // RNE
    return (unsigned short)(r >> 16);
}
__device__ __forceinline__ float bf2f(unsigned short h) {
    union { unsigned u; float f; } v; v.u = ((unsigned)h) << 16;
    return v.f;
}

// ---------------- K1: template path (LDS-staged, grid 128 = b x oc-quarter) ----------------
__global__ __launch_bounds__(256) void k1_template(
    const float* __restrict__ tmpl, const float* __restrict__ w_t,
    const float* __restrict__ gnw, const float* __restrict__ gnb,
    float* __restrict__ t_global, float* __restrict__ t_kernel)
{
    int b = blockIdx.x >> 2, h = blockIdx.x & 3;   // h: quarter of oc (16 oc)
    int tid = threadIdx.x;
    __shared__ float Xs[32][200];   // 32-ic chunk x 196 px (pad 200)
    __shared__ float T[16][200];
    __shared__ float sums[16], sumsq[16], A[16], Bb[16];
    float acc[16];
    #pragma unroll
    for (int o = 0; o < 16; ++o) acc[o] = 0.f;
    const float* wb = w_t + (h * 16) * 256;        // uniform -> s_load
    const float* tb = tmpl + b * 50176;
    int p = tid;
    for (int chunk = 0; chunk < 8; ++chunk) {
        __syncthreads();
        #pragma unroll
        for (int j = 0; j < 7; ++j) {
            int f4 = tid + (j << 8);
            if (f4 < 1568) {                        // 32 rows x 49 float4
                int ic = f4 / 49, px4 = (f4 - ic * 49) << 2;
                float4 v = *(const float4*)(tb + (chunk * 32 + ic) * 196 + px4);
                *(float4*)&Xs[ic][px4] = v;
            }
        }
        __syncthreads();
        if (p < 196) {
            for (int cc = 0; cc < 32; ++cc) {
                float xv = Xs[cc][p];
                #pragma unroll
                for (int o = 0; o < 16; ++o)
                    acc[o] += xv * wb[o * 256 + chunk * 32 + cc];
            }
        }
    }
    __syncthreads();
    if (p < 196) {
        #pragma unroll
        for (int o = 0; o < 16; ++o) T[o][p] = acc[o];
    }
    __syncthreads();
    if (tid < 16) {
        float s = 0.f, s2 = 0.f;
        for (int q = 0; q < 196; ++q) { float v = T[tid][q]; s += v; s2 += v * v; }
        sums[tid] = s; sumsq[tid] = s2;
    }
    __syncthreads();
    if (tid < 8) {   // group = channel pair, both in this block
        float S  = sums[2 * tid] + sums[2 * tid + 1];
        float S2 = sumsq[2 * tid] + sumsq[2 * tid + 1];
        float mean = S * (1.f / 392.f);
        float var  = S2 * (1.f / 392.f) - mean * mean;
        float inv  = rsqrtf(var + EPS);
        for (int e = 0; e < 2; ++e) {
            int c = 2 * tid + e, gc = h * 16 + c;
            float a = gnw[gc] * inv;
            A[c] = a; Bb[c] = gnb[gc] - mean * a;
        }
    }
    __syncthreads();
    if (p < 196) {
        #pragma unroll
        for (int o = 0; o < 16; ++o) {
            float v = A[o] * T[o][p] + Bb[o];
            T[o][p] = v > 0.f ? v : 0.f;
        }
    }
    __syncthreads();
    if (tid < 16) {
        int c = tid, gc = h * 16 + c;
        float s = 0.f;
        for (int q = 0; q < 196; ++q) s += T[c][q];
        t_global[b * 64 + gc] = s * (1.f / 196.f);
        for (int t = 0; t < 49; ++t) {
            int ky = t / 7, kx = t - 7 * ky;
            float v = T[c][(2 * ky) * 14 + 2 * kx]     + T[c][(2 * ky) * 14 + 2 * kx + 1]
                    + T[c][(2 * ky + 1) * 14 + 2 * kx] + T[c][(2 * ky + 1) * 14 + 2 * kx + 1];
            t_kernel[(b * 64 + gc) * 49 + t] = v * 0.25f;
        }
    }
}

// ---------------- K_PACK: w_s and w_p1 fp32 -> bf16 prepack (merged launch) ----------------
// blocks [0,64): w_s [oc][ic] -> bf16 same layout (16384 elems)
// blocks [64,208): w_p1 -> bf16 tap-major chunks of 32 (36864 elems)
__global__ __launch_bounds__(256) void k_pack(
    const float* __restrict__ w_s, unsigned short* __restrict__ wsb,
    const float* __restrict__ w1, unsigned short* __restrict__ wpk)
{
    int blk = blockIdx.x;
    if (blk < 64) {
        int i = blk * 256 + threadIdx.x;
        wsb[i] = f2bf(w_s[i]);
    } else {
        int i = (blk - 64) * 256 + threadIdx.x;
        if (i < 36864) {
            int c = i >> 11;
            int rem = i & 2047;
            int oc = rem >> 5;
            int k = rem & 31;
            int tap = c >> 1;
            int ic = ((c & 1) << 5) + k;
            wpk[i] = f2bf(w1[oc * 576 + ic * 9 + tap]);
        }
    }
}

// ---------------- K2: search conv1x1 via bf16 MFMA + fused GN stat partials ----------------
// grid (16 px-tiles, 32 b). Block: 256 px x 64 oc, K=256. M=oc (A=weights from global),
// N=px (B staged in LDS, xor-swizzled). fp32 NCHW output (downstream unchanged).
// Epilogue: per-oc partial sum/sumsq over this block's 256 px -> P1/P2[(b*16+tile)*64+oc].
__global__ __launch_bounds__(256) void k2_mfma(
    const float* __restrict__ x, const unsigned short* __restrict__ wsb,
    float* __restrict__ sraw, float* __restrict__ P1, float* __restrict__ P2)
{
    int b = blockIdx.y, p0 = blockIdx.x << 8;
    int tid = threadIdx.x;
    int wave = tid >> 6, lane = tid & 63, q = lane >> 4, l15 = lane & 15;
    __shared__ short tile[256 * 64];   // [px 256][ic 64] bf16, icblk xor-swizzled by px&7
    __shared__ float Ps[4][64], Ps2[4][64];

    floatx4 acc[4][4];
    #pragma unroll
    for (int i = 0; i < 4; ++i)
        #pragma unroll
        for (int mt = 0; mt < 4; ++mt) acc[i][mt] = (floatx4){0.f, 0.f, 0.f, 0.f};

    const float* xb = x + ((long)b << 20) + p0 + tid;   // px = p0 + tid, ic-stride 4096
    for (int chunk = 0; chunk < 4; ++chunk) {           // 64 ic per chunk
        __syncthreads();
        #pragma unroll
        for (int half = 0; half < 2; ++half) {
            float v[32];
            #pragma unroll
            for (int i = 0; i < 32; ++i)
                v[i] = xb[(long)((chunk << 6) + (half << 5) + i) << 12];
            #pragma unroll
            for (int blk = 0; blk < 4; ++blk) {
                int icblk = (half << 2) + blk;
                short8 s;
                #pragma unroll
                for (int e = 0; e < 8; ++e) s[e] = (short)f2bf(v[(blk << 3) + e]);
                int sw = icblk ^ (tid & 7);
                *(short8*)&tile[(tid << 6) + (sw << 3)] = s;
            }
        }
        __syncthreads();
        #pragma unroll
        for (int kq = 0; kq < 2; ++kq) {                // 32-ic MFMA chunks
            short8 afr[4], bfr[4];
            int kbase = (chunk << 6) + (kq << 5) + (q << 3);
            #pragma unroll
            for (int mt = 0; mt < 4; ++mt)
                afr[mt] = *(const short8*)(wsb + ((mt << 4) + l15) * 256 + kbase);
            #pragma unroll
            for (int i = 0; i < 4; ++i) {
                int px = (((wave << 2) + i) << 4) + l15;
                int sw = ((kq << 2) + q) ^ (px & 7);
                bfr[i] = *(const short8*)&tile[(px << 6) + (sw << 3)];
            }
            #pragma unroll
            for (int i = 0; i < 4; ++i)
                #pragma unroll
                for (int mt = 0; mt < 4; ++mt)
                    acc[i][mt] = __builtin_amdgcn_mfma_f32_16x16x32_bf16(afr[mt], bfr[i], acc[i][mt], 0, 0, 0);
        }
    }
    // D: col(lane&15)=px-in-tile, row(q*4+r)=oc-in-tile
    float* ob = sraw + ((long)b << 18) + p0;
    #pragma unroll
    for (int i = 0; i < 4; ++i) {
        int pxb = ((wave << 2) + i) << 4;
        #pragma unroll
        for (int mt = 0; mt < 4; ++mt)
            #pragma unroll
            for (int r = 0; r < 4; ++r) {
                int oc = (mt << 4) + (q << 2) + r;
                ob[(oc << 12) + pxb + l15] = acc[i][mt][r];
            }
    }
    // fused GN stat partials: wave covers px = wave*64 + i*16 + l15, oc = mt*16+q*4+r
    #pragma unroll
    for (int mt = 0; mt < 4; ++mt) {
        #pragma unroll
        for (int r = 0; r < 4; ++r) {
            float s = 0.f, s2 = 0.f;
            #pragma unroll
            for (int i = 0; i < 4; ++i) { float v = acc[i][mt][r]; s += v; s2 += v * v; }
            #pragma unroll
            for (int off = 1; off < 16; off <<= 1) {
                s  += __shfl_xor(s, off, 64);
                s2 += __shfl_xor(s2, off, 64);
            }
            if (l15 == 0) {
                int oc = (mt << 4) + (q << 2) + r;
                Ps[wave][oc] = s; Ps2[wave][oc] = s2;
            }
        }
    }
    __syncthreads();
    if (tid < 64) {
        float s  = Ps[0][tid] + Ps[1][tid] + Ps[2][tid] + Ps[3][tid];
        float s2 = Ps2[0][tid] + Ps2[1][tid] + Ps2[2][tid] + Ps2[3][tid];
        int idx = (((b << 4) + blockIdx.x) << 6) + tid;
        P1[idx] = s; P2[idx] = s2;
    }
}

// ---------------- K_FIN: finalize GN coefs from 16 per-tile partials ----------------
__global__ __launch_bounds__(64) void k_fin(
    const float* __restrict__ P1, const float* __restrict__ P2,
    const float* __restrict__ gnw, const float* __restrict__ gnb,
    float* __restrict__ A, float* __restrict__ Bc)
{
    int b = blockIdx.x, c = threadIdx.x;
    float s = 0.f, s2 = 0.f;
    for (int t = 0; t < 16; ++t) {
        int idx = (((b << 4) + t) << 6) + c;
        s += P1[idx]; s2 += P2[idx];
    }
    float sp = __shfl_xor(s, 1, 64), s2p = __shfl_xor(s2, 1, 64);
    float S = s + sp, S2 = s2 + s2p;
    float mean = S * (1.f / 8192.f);
    float var  = S2 * (1.f / 8192.f) - mean * mean;
    float inv  = rsqrtf(var + EPS);
    float a = gnw[c] * inv;
    A[b * 64 + c] = a;
    Bc[b * 64 + c] = gnb[c] - mean * a;
}

// ---------------- K4: corr = s*t_global + depthwise7x7 -> bf16 NCHW ----------------
__global__ __launch_bounds__(256) void k4_corr(
    const float* __restrict__ sraw, const float* __restrict__ A, const float* __restrict__ Bc,
    const float* __restrict__ t_global, const float* __restrict__ t_kernel,
    unsigned short* __restrict__ corr)
{
    int bc = blockIdx.x;
    int tid = threadIdx.x;
    __shared__ float tile[70 * 70];
    __shared__ float ker[49];
    float a = A[bc], bb = Bc[bc], tg = t_global[bc];
    for (int i = tid; i < 4900; i += 256) tile[i] = 0.f;
    if (tid < 49) ker[tid] = t_kernel[bc * 49 + tid];
    __syncthreads();
    const float* sb = sraw + ((long)bc << 12);
    for (int i = tid; i < 4096; i += 256) {
        int y = i >> 6, xx = i & 63;
        float v = a * sb[i] + bb;
        tile[(y + 3) * 70 + xx + 3] = v > 0.f ? v : 0.f;
    }
    __syncthreads();
    int x = tid & 63, ys = (tid >> 6) << 4;
    float acc[16];
    #pragma unroll
    for (int j = 0; j < 16; ++j) acc[j] = 0.f;
    #pragma unroll
    for (int kx = 0; kx < 7; ++kx) {
        float col[22];
        #pragma unroll
        for (int j = 0; j < 22; ++j) col[j] = tile[(ys + j) * 70 + x + kx];
        #pragma unroll
        for (int ky = 0; ky < 7; ++ky) {
            float kv = ker[ky * 7 + kx];
            #pragma unroll
            for (int j = 0; j < 16; ++j) acc[j] += kv * col[j + ky];
        }
    }
    unsigned short* ob = corr + ((long)bc << 12);
    #pragma unroll
    for (int j = 0; j < 16; ++j) {
        float sval = tile[(ys + j + 3) * 70 + x + 3];
        ob[((ys + j) << 6) + x] = f2bf(acc[j] + sval * tg);
    }
}

// ---------------- K_T: corr NCHW bf16 -> NHWC bf16 transpose ----------------
__global__ __launch_bounds__(256) void k_t(
    const unsigned short* __restrict__ corr, unsigned short* __restrict__ corrT)
{
    int py = blockIdx.x, b = blockIdx.y;
    int tid = threadIdx.x;
    __shared__ float T[64][65];
    {
        int c0 = tid >> 5, pxp = tid & 31;   // uint-packed loads: 2 px per thread
        const unsigned* src = (const unsigned*)(corr + (((long)b * 64) << 12) + (py << 6)) + pxp;
        #pragma unroll
        for (int i = 0; i < 8; ++i) {
            int c = c0 + (i << 3);
            unsigned u = src[(long)c << 11];   // c-stride 4096 shorts = 2048 uints
            T[c][2 * pxp]     = bf2f((unsigned short)(u & 0xFFFF));
            T[c][2 * pxp + 1] = bf2f((unsigned short)(u >> 16));
        }
    }
    __syncthreads();
    int ob = tid & 7, pxw = tid >> 3;
    unsigned short* dst = corrT + ((((b << 12)) + (py << 6)) << 6);
    #pragma unroll
    for (int i = 0; i < 2; ++i) {
        int p = pxw + (i << 5);
        unsigned w0 = (unsigned)f2bf(T[8 * ob + 0][p]) | ((unsigned)f2bf(T[8 * ob + 1][p]) << 16);
        unsigned w1 = (unsigned)f2bf(T[8 * ob + 2][p]) | ((unsigned)f2bf(T[8 * ob + 3][p]) << 16);
        unsigned w2 = (unsigned)f2bf(T[8 * ob + 4][p]) | ((unsigned)f2bf(T[8 * ob + 5][p]) << 16);
        unsigned w3 = (unsigned)f2bf(T[8 * ob + 6][p]) | ((unsigned)f2bf(T[8 * ob + 7][p]) << 16);
        uint4 val = {w0, w1, w2, w3};
        *(uint4*)(dst + ((long)p << 6) + (ob << 3)) = val;
    }
}

// ---------------- K5: conv3x3 via bf16 MFMA (NHWC in/out) + fused GN stat partials ----------------
__global__ __launch_bounds__(256) void k5_mfma(
    const unsigned short* __restrict__ corrT, const unsigned short* __restrict__ wpk,
    unsigned short* __restrict__ y, float* __restrict__ P1, float* __restrict__ P2)
{
    int b = blockIdx.y, py0 = blockIdx.x << 2;
    int tid = threadIdx.x;
    int wave = tid >> 6, lane = tid & 63, q = lane >> 4, l15 = lane & 15;
    __shared__ short tile[25344];   // [row 6][col 66][ic 64] bf16, xor-swizzled
    __shared__ float Ys[4][64], Ys2[4][64];

    for (int u = tid; u < 3168; u += 256) {
        int icblk = u & 7, rc = u >> 3;
        int row = rc / 66, col = rc - 66 * row;
        int py = py0 - 1 + row, px = col - 1;
        short8 v = {0, 0, 0, 0, 0, 0, 0, 0};
        if (py >= 0 && py < 64 && px >= 0 && px < 64)
            v = *(const short8*)(corrT + (((b << 12) + (py << 6) + px) << 6) + (icblk << 3));
        int sw = icblk ^ (col & 7);
        *(short8*)&tile[(rc << 6) + (sw << 3)] = v;
    }
    __syncthreads();

    floatx4 acc[4][4];
    #pragma unroll
    for (int i = 0; i < 4; ++i)
        #pragma unroll
        for (int ot = 0; ot < 4; ++ot) acc[i][ot] = (floatx4){0.f, 0.f, 0.f, 0.f};

    int pt0 = wave << 2;
    int rowb[4], colb[4];
    #pragma unroll
    for (int i = 0; i < 4; ++i) {
        int p = ((pt0 + i) << 4) + l15;
        rowb[i] = p >> 6;
        colb[i] = p & 63;
    }
    #pragma unroll
    for (int c = 0; c < 18; ++c) {
        const int tap = c >> 1, ky = tap / 3, kx = tap % 3, h = c & 1;
        short8 bfr[4], afr[4];
        #pragma unroll
        for (int ot = 0; ot < 4; ++ot)
            bfr[ot] = *(const short8*)(wpk + ((c << 6) + (ot << 4) + l15) * 32 + (q << 3));
        #pragma unroll
        for (int i = 0; i < 4; ++i) {
            int row = rowb[i] + ky, col = colb[i] + kx;
            int sw = ((h << 2) + q) ^ (col & 7);
            afr[i] = *(const short8*)&tile[((row * 66 + col) << 6) + (sw << 3)];
        }
        #pragma unroll
        for (int i = 0; i < 4; ++i)
            #pragma unroll
            for (int ot = 0; ot < 4; ++ot)
                acc[i][ot] = __builtin_amdgcn_mfma_f32_16x16x32_bf16(afr[i], bfr[ot], acc[i][ot], 0, 0, 0);
    }
    #pragma unroll
    for (int i = 0; i < 4; ++i) {
        #pragma unroll
        for (int r = 0; r < 4; ++r) {
            int p = ((pt0 + i) << 4) + (q << 2) + r;
            int py = py0 + (p >> 6), pxc = p & 63;
            int base = ((b << 12) + (py << 6) + pxc) << 6;
            #pragma unroll
            for (int ot = 0; ot < 4; ++ot)
                y[base + (ot << 4) + l15] = f2bf(acc[i][ot][r]);
        }
    }
    // fused GN stat partials: lane holds oc = ot*16 + l15; px rows vary over (i, q, r)
    #pragma unroll
    for (int ot = 0; ot < 4; ++ot) {
        float s = 0.f, s2 = 0.f;
        #pragma unroll
        for (int i = 0; i < 4; ++i)
            #pragma unroll
            for (int r = 0; r < 4; ++r) { float v = acc[i][ot][r]; s += v; s2 += v * v; }
        s += __shfl_xor(s, 16, 64); s2 += __shfl_xor(s2, 16, 64);
        s += __shfl_xor(s, 32, 64); s2 += __shfl_xor(s2, 32, 64);
        if (lane < 16) { Ys[wave][(ot << 4) + lane] = s; Ys2[wave][(ot << 4) + lane] = s2; }
    }
    __syncthreads();
    if (tid < 64) {
        float s  = Ys[0][tid] + Ys[1][tid] + Ys[2][tid] + Ys[3][tid];
        float s2 = Ys2[0][tid] + Ys2[1][tid] + Ys2[2][tid] + Ys2[3][tid];
        int idx = (((b << 4) + blockIdx.x) << 6) + tid;
        P1[idx] = s; P2[idx] = s2;
    }
}

// ---------------- K6: epilogue on NHWC bf16 y ----------------
__global__ __launch_bounds__(256) void k6_nhwc(
    const unsigned short* __restrict__ y, const float* __restrict__ A, const float* __restrict__ Bc,
    const float* __restrict__ w2, const float* __restrict__ b2, float* __restrict__ out)
{
    int b = blockIdx.y;
    int px0 = blockIdx.x << 9;
    int tid = threadIdx.x, wave = tid >> 6, lane = tid & 63;
    int ocp = lane & 31, ph = lane >> 5;
    int c0 = 2 * ocp;
    float a0 = A[b * 64 + c0],     b0 = Bc[b * 64 + c0],     w20 = w2[c0];
    float a1 = A[b * 64 + c0 + 1], b1 = Bc[b * 64 + c0 + 1], w21 = w2[c0 + 1];
    float bias = b2[0];
    const unsigned* yp = (const unsigned*)y;
    for (int i = 0; i < 64; ++i) {
        int px = px0 + (i << 3) + (wave << 1) + ph;
        unsigned u = yp[(((b << 12) + px) << 5) + ocp];
        float f0 = bf2f((unsigned short)(u & 0xFFFF));
        float f1 = bf2f((unsigned short)(u >> 16));
        float v0 = a0 * f0 + b0; v0 = v0 > 0.f ? v0 : 0.f;
        float v1 = a1 * f1 + b1; v1 = v1 > 0.f ? v1 : 0.f;
        float val = w20 * v0 + w21 * v1;
        #pragma unroll
        for (int m = 16; m >= 1; m >>= 1) val += __shfl_xor(val, m, 64);
        if (ocp == 0) out[(b << 12) + px] = val + bias;
    }
}

extern "C" void kernel_launch(void* const* d_in, const int* in_sizes, int n_in,
                              void* d_out, int out_size, void* d_ws, size_t ws_size,
                              hipStream_t stream)
{
    const float* tmpl   = (const float*)d_in[0];
    const float* search = (const float*)d_in[1];
    const float* w_t    = (const float*)d_in[2];
    const float* gn_t_w = (const float*)d_in[3];
    const float* gn_t_b = (const float*)d_in[4];
    const float* w_s    = (const float*)d_in[5];
    const float* gn_s_w = (const float*)d_in[6];
    const float* gn_s_b = (const float*)d_in[7];
    const float* w_p1   = (const float*)d_in[8];
    const float* gn_p_w = (const float*)d_in[9];
    const float* gn_p_b = (const float*)d_in[10];
    const float* w_p2   = (const float*)d_in[11];
    const float* b_p2   = (const float*)d_in[12];
    float* out = (float*)d_out;
    float* ws  = (float*)d_ws;

    float* TG   = ws;                    // 2048
    float* TK   = ws + 2048;             // 100352 -> ends 102400
    float* AS   = ws + 102400;           // 2048
    float* BS   = ws + 104448;           // 2048
    float* AY   = ws + 106496;           // 2048
    float* BY   = ws + 108544;           // 2048 -> ends 110592
    float* P1   = ws + 110592;           // 32768 (32b x 16 tiles x 64 oc) -> ends 143360
    float* P2   = ws + 143360;           // 32768 -> ends 176128
    unsigned short* WPK = (unsigned short*)(ws + 176128);   // 36864 bf16 -> ends (float) 194560
    float* SRAW = ws + 196608;           // 8388608 floats (32 MB) -> ends 8585216
    unsigned short* CORRB = (unsigned short*)(ws + 8585216); // 4194304 bf16 (8 MB)
    // overlays (timeline-disjoint):
    unsigned short* WSB   = (unsigned short*)CORRB;          // dead once k2 done; k4 overwrites
    unsigned short* YRAW  = (unsigned short*)SRAW;           // k5 writes after SRAW dead (k4 last reader)
    unsigned short* CORRT = (unsigned short*)(SRAW + 4194304);

    k_pack<<<208, 256, 0, stream>>>(w_s, WSB, w_p1, WPK);
    k1_template<<<128, 256, 0, stream>>>(tmpl, w_t, gn_t_w, gn_t_b, TG, TK);
    k2_mfma<<<dim3(16, 32), 256, 0, stream>>>(search, WSB, SRAW, P1, P2);
    k_fin<<<32, 64, 0, stream>>>(P1, P2, gn_s_w, gn_s_b, AS, BS);
    k4_corr<<<2048, 256, 0, stream>>>(SRAW, AS, BS, TG, TK, CORRB);
    k_t<<<dim3(64, 32), 256, 0, stream>>>(CORRB, CORRT);
    k5_mfma<<<dim3(16, 32), 256, 0, stream>>>(CORRT, WPK, YRAW, P1, P2);
    k_fin<<<32, 64, 0, stream>>>(P1, P2, gn_p_w, gn_p_b, AY, BY);
    k6_nhwc<<<dim3(8, 32), 256, 0, stream>>>(YRAW, AY, BY, w_p2, b_p2, out);
}